// Round 18
// baseline (215.424 us; speedup 1.0000x reference)
//
#include <hip/hip_runtime.h>
#include <hip/hip_bf16.h>
#include <math.h>

typedef __attribute__((ext_vector_type(8))) __bf16 bf16x8;
typedef __attribute__((ext_vector_type(4))) float f32x4;
typedef __attribute__((ext_vector_type(16))) float f32x16;
typedef __attribute__((ext_vector_type(2))) unsigned u32x2;

#define MFMA16(a, b, c) __builtin_amdgcn_mfma_f32_16x16x32_bf16((a), (b), (c), 0, 0, 0)
#define MFMA32(a, b, c) __builtin_amdgcn_mfma_f32_32x32x16_bf16((a), (b), (c), 0, 0, 0)

#define GLOAD_LDS(g, l)                                                                     \
  __builtin_amdgcn_global_load_lds((const __attribute__((address_space(1))) unsigned int*)(g), \
                                   (__attribute__((address_space(3))) unsigned int*)(l), 16, 0, 0)

static constexpr int Bb  = 2;
static constexpr int Nn  = 2048;
static constexpr int Dd  = 2048;
static constexpr int Hh  = 8;
static constexpr int Gg  = 4;
static constexpr int Cc  = 64;    // head dim
static constexpr int KVW = 1024;  // 2*H*C

__device__ __forceinline__ unsigned short f2bf(float f) {
  unsigned int u = __float_as_uint(f);
  u += 0x7FFFu + ((u >> 16) & 1u);   // RNE
  return (unsigned short)(u >> 16);
}

// exp2 via compiler-visible intrinsic (r16-verified: only INLINE-ASM consumers are
// hazard-unprotected; builtins are fine). Fallback mathematically identical.
#if __has_builtin(__builtin_amdgcn_exp2f)
__device__ __forceinline__ float fexp2(float x) { return __builtin_amdgcn_exp2f(x); }
#else
__device__ __forceinline__ float fexp2(float x) { return __expf(x * 0.6931471805599453f); }
#endif

// ---- fused prep: xconv + all three weight convert/transpose in ONE dispatch ----
__global__ void prep(const float* __restrict__ x, unsigned short* __restrict__ xb,
                     const float* __restrict__ Wq, unsigned short* __restrict__ Wqt,
                     const float* __restrict__ Wkv, unsigned short* __restrict__ Wkvt,
                     const float* __restrict__ Wp, unsigned short* __restrict__ Wpt,
                     float qscale) {
  __shared__ float t[32][33];
  int bx = blockIdx.x;
  if (bx < 1024) {
    const int n4 = (Bb * Nn * Dd) / 4;
    int i = bx * 256 + threadIdx.x;
    for (; i < n4; i += 1024 * 256) {
      float4 v = ((const float4*)x)[i];
      ushort4 o;
      o.x = f2bf(v.x); o.y = f2bf(v.y); o.z = f2bf(v.z); o.w = f2bf(v.w);
      ((ushort4*)xb)[i] = o;
    }
    return;
  }
  bx -= 1024;
  const float* W;
  unsigned short* Wt;
  int N, nsh;
  float scale;
  if (bx < 4096) {
    W = Wq; Wt = Wqt; N = Dd; nsh = 6; scale = qscale;
  } else if (bx < 6144) {
    bx -= 4096; W = Wkv; Wt = Wkvt; N = KVW; nsh = 5; scale = 1.0f;
  } else {
    bx -= 6144; W = Wp; Wt = Wpt; N = Dd; nsh = 6; scale = 1.0f;
  }
  const int n0 = (bx & ((1 << nsh) - 1)) * 32;
  const int k0 = (bx >> nsh) * 32;
  for (int i = threadIdx.x; i < 1024; i += blockDim.x) {
    int r = i >> 5, c = i & 31;
    t[r][c] = W[(size_t)(k0 + r) * N + n0 + c];
  }
  __syncthreads();
  for (int i = threadIdx.x; i < 1024; i += blockDim.x) {
    int r = i >> 5, c = i & 31;
    Wt[(size_t)(n0 + r) * Dd + k0 + c] = f2bf(t[c][r] * scale);
  }
}

// ------- GEMM (r11-verified structure, templated on BM, optional V^T epilogue) ----
template <int BM, bool OUTF32, bool VOUT = false>
__global__ __launch_bounds__(256, 2)
void gemm_bt(const unsigned short* __restrict__ A, const unsigned short* __restrict__ Bt,
             unsigned short* __restrict__ Cb, float* __restrict__ Cf,
             const float* __restrict__ bias, unsigned short* __restrict__ vTo,
             int M, int N, int K) {
  constexpr int BN = 128;
  constexpr int CA = BM / 8;
  constexpr int CB = BN / 8;
  constexpr int APW = CA / 4, BPW = CB / 4;
  constexpr int MT = BM / 32, NT = BN / 32;
  __shared__ unsigned short As[2][BM * 64];
  __shared__ unsigned short Bs[2][BN * 64];
  const int tid = threadIdx.x;
  const int wid = tid >> 6, lane = tid & 63;
  const size_t m0 = (size_t)blockIdx.x * BM;
  const size_t n0 = (size_t)blockIdx.y * BN;
  const int nk = K >> 6;

  const int sub = lane >> 3, slot = lane & 7;
  const int gslot = slot ^ sub;
  const unsigned short* gA[APW];
  const unsigned short* gB[BPW];
#pragma unroll
  for (int i = 0; i < APW; ++i) {
    const int c = wid * APW + i;
    gA[i] = A + (m0 + c * 8 + sub) * (size_t)K + gslot * 8;
  }
#pragma unroll
  for (int i = 0; i < BPW; ++i) {
    const int c = wid * BPW + i;
    gB[i] = Bt + (n0 + c * 8 + sub) * (size_t)K + gslot * 8;
  }

  auto stage = [&](int bi) {
#pragma unroll
    for (int i = 0; i < APW; ++i) {
      GLOAD_LDS(gA[i], &As[bi][(wid * APW + i) * 512]);
      gA[i] += 64;
    }
#pragma unroll
    for (int i = 0; i < BPW; ++i) {
      GLOAD_LDS(gB[i], &Bs[bi][(wid * BPW + i) * 512]);
      gB[i] += 64;
    }
  };

  const int wr = wid >> 1, wc = wid & 1;
  const int lrow = lane & 15, lg = lane >> 4;
  int aoff[MT][2], boff[NT][2];
#pragma unroll
  for (int mt = 0; mt < MT; ++mt)
#pragma unroll
    for (int kc = 0; kc < 2; ++kc) {
      const int sl = (((kc << 2) + lg) ^ (lrow & 7)) << 4;
      aoff[mt][kc] = (wr * (BM / 2) + mt * 16 + lrow) * 128 + sl;
    }
#pragma unroll
  for (int nt = 0; nt < NT; ++nt)
#pragma unroll
    for (int kc = 0; kc < 2; ++kc) {
      const int sl = (((kc << 2) + lg) ^ (lrow & 7)) << 4;
      boff[nt][kc] = (wc * (BN / 2) + nt * 16 + lrow) * 128 + sl;
    }

  const f32x4 zero = {0.f, 0.f, 0.f, 0.f};
  f32x4 acc[MT][NT];
#pragma unroll
  for (int i = 0; i < MT; ++i)
#pragma unroll
    for (int j = 0; j < NT; ++j) acc[i][j] = zero;

  auto compute = [&](int bi) {
    const char* Ab = (const char*)&As[bi][0];
    const char* Bb2 = (const char*)&Bs[bi][0];
#pragma unroll
    for (int kc = 0; kc < 2; ++kc) {
      bf16x8 af[MT], bfr[NT];
#pragma unroll
      for (int mt = 0; mt < MT; ++mt) af[mt] = *(const bf16x8*)(Ab + aoff[mt][kc]);
#pragma unroll
      for (int nt = 0; nt < NT; ++nt) bfr[nt] = *(const bf16x8*)(Bb2 + boff[nt][kc]);
#pragma unroll
      for (int mt = 0; mt < MT; ++mt)
#pragma unroll
        for (int nt = 0; nt < NT; ++nt) acc[mt][nt] = MFMA16(af[mt], bfr[nt], acc[mt][nt]);
    }
  };

  stage(0);
  __syncthreads();
  for (int kt = 0; kt < nk; kt += 2) {
    stage(1);
    compute(0);
    __syncthreads();
    if (kt + 2 < nk) stage(0);
    compute(1);
    __syncthreads();
  }

  if (VOUT && n0 >= 512) {
#pragma unroll
    for (int mt = 0; mt < MT; ++mt)
#pragma unroll
      for (int nt = 0; nt < NT; ++nt) {
        const int colv = (int)(n0 - 512) + wc * (BN / 2) + nt * 16 + lrow;
        const int h = colv >> 6, c = colv & 63;
        const size_t r0 = m0 + wr * (BM / 2) + mt * 16 + lg * 4;
        const int b = (int)(r0 >> 11);
        const int s = (int)(r0 & 2047);
        ushort4 o;
        o.x = f2bf(acc[mt][nt][0]);
        o.y = f2bf(acc[mt][nt][1]);
        o.z = f2bf(acc[mt][nt][2]);
        o.w = f2bf(acc[mt][nt][3]);
        *(ushort4*)&vTo[(((size_t)b * Hh + h) * Cc + c) * (size_t)Nn + s] = o;
      }
    return;
  }

#pragma unroll
  for (int mt = 0; mt < MT; ++mt)
#pragma unroll
    for (int nt = 0; nt < NT; ++nt) {
      const size_t col = n0 + wc * (BN / 2) + nt * 16 + lrow;
#pragma unroll
      for (int i = 0; i < 4; ++i) {
        const size_t r = m0 + wr * (BM / 2) + mt * 16 + lg * 4 + i;
        if constexpr (OUTF32)
          Cf[r * N + col] = acc[mt][nt][i] + bias[col];
        else
          Cb[r * N + col] = f2bf(acc[mt][nt][i]);
      }
    }
}

// ------- fused flash attention, round-18: T15 phase interleave within super-tile ----
// KVBLK=128 (r17 skeleton/barriers unchanged). Phase order per buffer is now
// QK0 -> exp0 -> QK1 -> PV0 -> exp1 -> PV1: PV0 (depends only on pka) issues behind
// QK1's independent MFMAs (20 MFMA, 7 indep chains fill the pipe); exp1's VALU
// overlaps the PV drain. Pure source reorder of r16/r17-verified ops — no barrier,
// offset, or math changes. Register peak ~126 <= the 128 cap of launch_bounds(512,4).
__global__ __launch_bounds__(512, 4)
void attn_kernel(const unsigned short* __restrict__ qb, const unsigned short* __restrict__ kvb,
                 const unsigned short* __restrict__ vT, unsigned short* __restrict__ ob) {
  __shared__ unsigned short Ks[2][2][4096];  // [buf][sub][64x64 swizzled]
  __shared__ unsigned short Vs[2][2][4096];
  const int tid = threadIdx.x;
  const int wid = tid >> 6, lane = tid & 63;
  const int r31 = lane & 31, hi = lane >> 5, r7 = r31 & 7;
  const int q0 = blockIdx.x * 256 + wid * 32;
  const int bhg = blockIdx.y;
  const int b = bhg >> 5, h = (bhg >> 2) & 7, g = bhg & 3;

  const unsigned short* kptr = kvb + (size_t)b * Nn * KVW + h * Cc;
  const unsigned short* vptr = vT + (size_t)(b * Hh + h) * Cc * Nn;

  const int sub = lane >> 3, slot = lane & 7;
  const int gslot = slot ^ sub;
  const unsigned short* gk = kptr + (size_t)(wid * 8 + sub) * KVW + gslot * 8;
  const unsigned short* gv = vptr + (size_t)(wid * 8 + sub) * Nn + gslot * 8;

  bf16x8 qf[4];
  {
    const unsigned short* qrow =
        qb + ((size_t)b * Nn + q0 + r31) * Dd + h * (Gg * Cc) + g * Cc + hi * 8;
#pragma unroll
    for (int ks = 0; ks < 4; ++ks) qf[ks] = *(const bf16x8*)(qrow + ks * 16);
  }

  union { unsigned u[4]; bf16x8 v; } ones;
  ones.u[0] = ones.u[1] = ones.u[2] = ones.u[3] = 0x3F803F80u;

  int off[4];
#pragma unroll
  for (int ks = 0; ks < 4; ++ks) off[ks] = r31 * 128 + (((2 * ks + hi) ^ r7) << 4);

  f32x16 O0 = (f32x16)0.0f, O1 = (f32x16)0.0f, Lacc = (f32x16)0.0f;

  auto stage = [&](int bi) {
    GLOAD_LDS(gk, &Ks[bi][0][wid * 512]);
    GLOAD_LDS(gk + (size_t)64 * KVW, &Ks[bi][1][wid * 512]);
    GLOAD_LDS(gv, &Vs[bi][0][wid * 512]);
    GLOAD_LDS(gv + 64, &Vs[bi][1][wid * 512]);
    gk += (size_t)128 * KVW;
    gv += 128;
  };

  auto qk = [&](const char* Kb, f32x16& S0, f32x16& S1) {
    __builtin_amdgcn_s_setprio(1);
#pragma unroll
    for (int ks = 0; ks < 4; ++ks) {
      bf16x8 k0 = *(const bf16x8*)(Kb + off[ks]);
      bf16x8 k1 = *(const bf16x8*)(Kb + off[ks] + 4096);
      S0 = MFMA32(k0, qf[ks], S0);
      S1 = MFMA32(k1, qf[ks], S1);
    }
    __builtin_amdgcn_s_setprio(0);
  };

  auto exppack = [&](const f32x16& S0, const f32x16& S1, unsigned* pk) {
#pragma unroll
    for (int kt2 = 0; kt2 < 2; ++kt2)
#pragma unroll
      for (int blk = 0; blk < 4; ++blk)
#pragma unroll
        for (int m = 0; m < 2; ++m) {
          float pa = fexp2(kt2 ? S1[4 * blk + 2 * m] : S0[4 * blk + 2 * m]);
          float pb = fexp2(kt2 ? S1[4 * blk + 2 * m + 1] : S0[4 * blk + 2 * m + 1]);
          pk[kt2 * 8 + blk * 2 + m] = __builtin_amdgcn_perm(
              __float_as_uint(pb), __float_as_uint(pa), 0x07060302u);
        }
  };

  auto pv = [&](const char* Vb, const unsigned* pk) {
    __builtin_amdgcn_s_setprio(1);
#pragma unroll
    for (int vs = 0; vs < 4; ++vs) {
      const int base = (vs >> 1) * 8 + (vs & 1) * 4;
      u32x2 rA = __builtin_amdgcn_permlane32_swap(pk[base + 0], pk[base + 2], false, false);
      u32x2 rB = __builtin_amdgcn_permlane32_swap(pk[base + 1], pk[base + 3], false, false);
      union { unsigned u[4]; bf16x8 v; } pf;
      pf.u[0] = rA.x; pf.u[1] = rB.x; pf.u[2] = rA.y; pf.u[3] = rB.y;
      bf16x8 v0 = *(const bf16x8*)(Vb + off[vs]);
      bf16x8 v1 = *(const bf16x8*)(Vb + off[vs] + 4096);
      O0 = MFMA32(pf.v, v0, O0);
      O1 = MFMA32(pf.v, v1, O1);
      Lacc = MFMA32(pf.v, ones.v, Lacc);
    }
    __builtin_amdgcn_s_setprio(0);
  };

  // Interleaved super-tile: QK0, exp0, QK1, PV0, exp1, PV1
  auto compute2 = [&](int bi) {
    const char* K0 = (const char*)Ks[bi][0];
    const char* V0 = (const char*)Vs[bi][0];
    const char* K1 = (const char*)Ks[bi][1];
    const char* V1 = (const char*)Vs[bi][1];
    f32x16 Sa0 = (f32x16)0.0f, Sa1 = (f32x16)0.0f;
    qk(K0, Sa0, Sa1);
    unsigned pka[16];
    exppack(Sa0, Sa1, pka);
    f32x16 Sb0 = (f32x16)0.0f, Sb1 = (f32x16)0.0f;
    qk(K1, Sb0, Sb1);
    pv(V0, pka);
    unsigned pkb[16];
    exppack(Sb0, Sb1, pkb);
    pv(V1, pkb);
  };

  stage(0);
  __syncthreads();
  for (int t = 0; t < Nn / 128; t += 2) {
    stage(1);
    compute2(0);
    __syncthreads();
    if (t + 2 < Nn / 128) stage(0);
    compute2(1);
    __syncthreads();
  }

  const size_t orow_base = (size_t)b * Nn + q0;
  const int ocol = h * (Gg * Cc) + g * Cc;
#pragma unroll
  for (int r = 0; r < 16; ++r) {
    const int q_r = (r & 3) + 8 * (r >> 2) + 4 * hi;
    const float li = 1.0f / Lacc[r];
    const size_t basep = (orow_base + q_r) * Dd + ocol;
    ob[basep + r31] = f2bf(O0[r] * li);
    ob[basep + 32 + r31] = f2bf(O1[r] * li);
  }
}

extern "C" void kernel_launch(void* const* d_in, const int* in_sizes, int n_in,
                              void* d_out, int out_size, void* d_ws, size_t ws_size,
                              hipStream_t stream) {
  const float* x   = (const float*)d_in[0];
  const float* Wq  = (const float*)d_in[1];
  const float* Wkv = (const float*)d_in[2];
  const float* Wp  = (const float*)d_in[3];
  const float* bp  = (const float*)d_in[4];
  float* out = (float*)d_out;

  char* ws = (char*)d_ws;
  size_t off = 0;
  auto alloc = [&](size_t bytes) {
    char* p = ws + off;
    off += (bytes + 255) & ~(size_t)255;
    return p;
  };
  unsigned short* xb   = (unsigned short*)alloc((size_t)Bb * Nn * Dd * 2);
  unsigned short* Wqt  = (unsigned short*)alloc((size_t)Dd * Dd * 2);
  unsigned short* Wkvt = (unsigned short*)alloc((size_t)KVW * Dd * 2);
  unsigned short* Wpt  = (unsigned short*)alloc((size_t)Dd * Dd * 2);
  unsigned short* qbf  = (unsigned short*)alloc((size_t)Bb * Nn * Dd * 2);
  unsigned short* kvb  = (unsigned short*)alloc((size_t)Bb * Nn * KVW * 2);
  unsigned short* vT   = (unsigned short*)alloc((size_t)Bb * Hh * Cc * Nn * 2);
  unsigned short* ob   = xb;  // reuse: xb dead after the KV GEMM

  const int M = Bb * Nn;  // 4096
  // 1/sqrt(32) * log2(e): softmax in exp2 domain via fexp2 (identical math)
  const float qscale = 0.17677669529663687f * 1.4426950408889634f;

  prep<<<11264, 256, 0, stream>>>(x, xb, Wq, Wqt, Wkv, Wkvt, Wp, Wpt, qscale);

  gemm_bt<128, false><<<dim3(M / 128, Dd / 128), 256, 0, stream>>>(
      xb, Wqt, qbf, nullptr, nullptr, nullptr, M, Dd, Dd);
  gemm_bt<64, false, true><<<dim3(M / 64, KVW / 128), 256, 0, stream>>>(
      xb, Wkvt, kvb, nullptr, nullptr, vT, M, KVW, Dd);
  attn_kernel<<<dim3(Nn / 256, Bb * Hh * Gg), 512, 0, stream>>>(qbf, kvb, vT, ob);
  gemm_bt<128, true><<<dim3(M / 128, Dd / 128), 256, 0, stream>>>(
      ob, Wpt, nullptr, out, bp, nullptr, M, Dd, Dd);
}

// Round 19
// 207.769 us; speedup vs baseline: 1.0368x; 1.0368x over previous
//
#include <hip/hip_runtime.h>
#include <hip/hip_bf16.h>
#include <math.h>

typedef __attribute__((ext_vector_type(8))) __bf16 bf16x8;
typedef __attribute__((ext_vector_type(4))) float f32x4;
typedef __attribute__((ext_vector_type(16))) float f32x16;
typedef __attribute__((ext_vector_type(2))) unsigned u32x2;

#define MFMA16(a, b, c) __builtin_amdgcn_mfma_f32_16x16x32_bf16((a), (b), (c), 0, 0, 0)
#define MFMA32(a, b, c) __builtin_amdgcn_mfma_f32_32x32x16_bf16((a), (b), (c), 0, 0, 0)

#define GLOAD_LDS(g, l)                                                                     \
  __builtin_amdgcn_global_load_lds((const __attribute__((address_space(1))) unsigned int*)(g), \
                                   (__attribute__((address_space(3))) unsigned int*)(l), 16, 0, 0)

static constexpr int Bb  = 2;
static constexpr int Nn  = 2048;
static constexpr int Dd  = 2048;
static constexpr int Hh  = 8;
static constexpr int Gg  = 4;
static constexpr int Cc  = 64;    // head dim
static constexpr int KVW = 1024;  // 2*H*C

__device__ __forceinline__ unsigned short f2bf(float f) {
  unsigned int u = __float_as_uint(f);
  u += 0x7FFFu + ((u >> 16) & 1u);   // RNE
  return (unsigned short)(u >> 16);
}

// exp2 via compiler-visible intrinsic (r16-verified: only INLINE-ASM consumers are
// hazard-unprotected; builtins are fine). Fallback mathematically identical.
#if __has_builtin(__builtin_amdgcn_exp2f)
__device__ __forceinline__ float fexp2(float x) { return __builtin_amdgcn_exp2f(x); }
#else
__device__ __forceinline__ float fexp2(float x) { return __expf(x * 0.6931471805599453f); }
#endif

// ---- fused prep: xconv + all three weight convert/transpose in ONE dispatch ----
__global__ void prep(const float* __restrict__ x, unsigned short* __restrict__ xb,
                     const float* __restrict__ Wq, unsigned short* __restrict__ Wqt,
                     const float* __restrict__ Wkv, unsigned short* __restrict__ Wkvt,
                     const float* __restrict__ Wp, unsigned short* __restrict__ Wpt,
                     float qscale) {
  __shared__ float t[32][33];
  int bx = blockIdx.x;
  if (bx < 1024) {
    const int n4 = (Bb * Nn * Dd) / 4;
    int i = bx * 256 + threadIdx.x;
    for (; i < n4; i += 1024 * 256) {
      float4 v = ((const float4*)x)[i];
      ushort4 o;
      o.x = f2bf(v.x); o.y = f2bf(v.y); o.z = f2bf(v.z); o.w = f2bf(v.w);
      ((ushort4*)xb)[i] = o;
    }
    return;
  }
  bx -= 1024;
  const float* W;
  unsigned short* Wt;
  int N, nsh;
  float scale;
  if (bx < 4096) {
    W = Wq; Wt = Wqt; N = Dd; nsh = 6; scale = qscale;
  } else if (bx < 6144) {
    bx -= 4096; W = Wkv; Wt = Wkvt; N = KVW; nsh = 5; scale = 1.0f;
  } else {
    bx -= 6144; W = Wp; Wt = Wpt; N = Dd; nsh = 6; scale = 1.0f;
  }
  const int n0 = (bx & ((1 << nsh) - 1)) * 32;
  const int k0 = (bx >> nsh) * 32;
  for (int i = threadIdx.x; i < 1024; i += blockDim.x) {
    int r = i >> 5, c = i & 31;
    t[r][c] = W[(size_t)(k0 + r) * N + n0 + c];
  }
  __syncthreads();
  for (int i = threadIdx.x; i < 1024; i += blockDim.x) {
    int r = i >> 5, c = i & 31;
    Wt[(size_t)(n0 + r) * Dd + k0 + c] = f2bf(t[c][r] * scale);
  }
}

// ------- GEMM (r11-verified structure, templated on BM, optional V^T epilogue) ----
template <int BM, bool OUTF32, bool VOUT = false>
__global__ __launch_bounds__(256, 2)
void gemm_bt(const unsigned short* __restrict__ A, const unsigned short* __restrict__ Bt,
             unsigned short* __restrict__ Cb, float* __restrict__ Cf,
             const float* __restrict__ bias, unsigned short* __restrict__ vTo,
             int M, int N, int K) {
  constexpr int BN = 128;
  constexpr int CA = BM / 8;
  constexpr int CB = BN / 8;
  constexpr int APW = CA / 4, BPW = CB / 4;
  constexpr int MT = BM / 32, NT = BN / 32;
  __shared__ unsigned short As[2][BM * 64];
  __shared__ unsigned short Bs[2][BN * 64];
  const int tid = threadIdx.x;
  const int wid = tid >> 6, lane = tid & 63;
  const size_t m0 = (size_t)blockIdx.x * BM;
  const size_t n0 = (size_t)blockIdx.y * BN;
  const int nk = K >> 6;

  const int sub = lane >> 3, slot = lane & 7;
  const int gslot = slot ^ sub;
  const unsigned short* gA[APW];
  const unsigned short* gB[BPW];
#pragma unroll
  for (int i = 0; i < APW; ++i) {
    const int c = wid * APW + i;
    gA[i] = A + (m0 + c * 8 + sub) * (size_t)K + gslot * 8;
  }
#pragma unroll
  for (int i = 0; i < BPW; ++i) {
    const int c = wid * BPW + i;
    gB[i] = Bt + (n0 + c * 8 + sub) * (size_t)K + gslot * 8;
  }

  auto stage = [&](int bi) {
#pragma unroll
    for (int i = 0; i < APW; ++i) {
      GLOAD_LDS(gA[i], &As[bi][(wid * APW + i) * 512]);
      gA[i] += 64;
    }
#pragma unroll
    for (int i = 0; i < BPW; ++i) {
      GLOAD_LDS(gB[i], &Bs[bi][(wid * BPW + i) * 512]);
      gB[i] += 64;
    }
  };

  const int wr = wid >> 1, wc = wid & 1;
  const int lrow = lane & 15, lg = lane >> 4;
  int aoff[MT][2], boff[NT][2];
#pragma unroll
  for (int mt = 0; mt < MT; ++mt)
#pragma unroll
    for (int kc = 0; kc < 2; ++kc) {
      const int sl = (((kc << 2) + lg) ^ (lrow & 7)) << 4;
      aoff[mt][kc] = (wr * (BM / 2) + mt * 16 + lrow) * 128 + sl;
    }
#pragma unroll
  for (int nt = 0; nt < NT; ++nt)
#pragma unroll
    for (int kc = 0; kc < 2; ++kc) {
      const int sl = (((kc << 2) + lg) ^ (lrow & 7)) << 4;
      boff[nt][kc] = (wc * (BN / 2) + nt * 16 + lrow) * 128 + sl;
    }

  const f32x4 zero = {0.f, 0.f, 0.f, 0.f};
  f32x4 acc[MT][NT];
#pragma unroll
  for (int i = 0; i < MT; ++i)
#pragma unroll
    for (int j = 0; j < NT; ++j) acc[i][j] = zero;

  auto compute = [&](int bi) {
    const char* Ab = (const char*)&As[bi][0];
    const char* Bb2 = (const char*)&Bs[bi][0];
#pragma unroll
    for (int kc = 0; kc < 2; ++kc) {
      bf16x8 af[MT], bfr[NT];
#pragma unroll
      for (int mt = 0; mt < MT; ++mt) af[mt] = *(const bf16x8*)(Ab + aoff[mt][kc]);
#pragma unroll
      for (int nt = 0; nt < NT; ++nt) bfr[nt] = *(const bf16x8*)(Bb2 + boff[nt][kc]);
#pragma unroll
      for (int mt = 0; mt < MT; ++mt)
#pragma unroll
        for (int nt = 0; nt < NT; ++nt) acc[mt][nt] = MFMA16(af[mt], bfr[nt], acc[mt][nt]);
    }
  };

  stage(0);
  __syncthreads();
  for (int kt = 0; kt < nk; kt += 2) {
    stage(1);
    compute(0);
    __syncthreads();
    if (kt + 2 < nk) stage(0);
    compute(1);
    __syncthreads();
  }

  if (VOUT && n0 >= 512) {
#pragma unroll
    for (int mt = 0; mt < MT; ++mt)
#pragma unroll
      for (int nt = 0; nt < NT; ++nt) {
        const int colv = (int)(n0 - 512) + wc * (BN / 2) + nt * 16 + lrow;
        const int h = colv >> 6, c = colv & 63;
        const size_t r0 = m0 + wr * (BM / 2) + mt * 16 + lg * 4;
        const int b = (int)(r0 >> 11);
        const int s = (int)(r0 & 2047);
        ushort4 o;
        o.x = f2bf(acc[mt][nt][0]);
        o.y = f2bf(acc[mt][nt][1]);
        o.z = f2bf(acc[mt][nt][2]);
        o.w = f2bf(acc[mt][nt][3]);
        *(ushort4*)&vTo[(((size_t)b * Hh + h) * Cc + c) * (size_t)Nn + s] = o;
      }
    return;
  }

#pragma unroll
  for (int mt = 0; mt < MT; ++mt)
#pragma unroll
    for (int nt = 0; nt < NT; ++nt) {
      const size_t col = n0 + wc * (BN / 2) + nt * 16 + lrow;
#pragma unroll
      for (int i = 0; i < 4; ++i) {
        const size_t r = m0 + wr * (BM / 2) + mt * 16 + lg * 4 + i;
        if constexpr (OUTF32)
          Cf[r * N + col] = acc[mt][nt][i] + bias[col];
        else
          Cb[r * N + col] = f2bf(acc[mt][nt][i]);
      }
    }
}

// ------- fused flash attention (r17-verified, REVERTED from r18's interleave which
// spilled to scratch: FETCH +14%, MfmaUtil 50.5->46, dur 75.3->81.7) -------
// KVBLK=128, two sequential compute() calls per barrier; swapped-QK^T 32x32,
// static-max, perm-truncation P-pack, L via ones-MFMA, exp2 builtin.
__global__ __launch_bounds__(512, 4)
void attn_kernel(const unsigned short* __restrict__ qb, const unsigned short* __restrict__ kvb,
                 const unsigned short* __restrict__ vT, unsigned short* __restrict__ ob) {
  __shared__ unsigned short Ks[2][2][4096];  // [buf][sub: key 64-group][64x64 swizzled]
  __shared__ unsigned short Vs[2][2][4096];  // [buf][sub: s 64-group][64(c)x64(s) swizzled]
  const int tid = threadIdx.x;
  const int wid = tid >> 6, lane = tid & 63;
  const int r31 = lane & 31, hi = lane >> 5, r7 = r31 & 7;
  const int q0 = blockIdx.x * 256 + wid * 32;
  const int bhg = blockIdx.y;
  const int b = bhg >> 5, h = (bhg >> 2) & 7, g = bhg & 3;

  const unsigned short* kptr = kvb + (size_t)b * Nn * KVW + h * Cc;
  const unsigned short* vptr = vT + (size_t)(b * Hh + h) * Cc * Nn;

  const int sub = lane >> 3, slot = lane & 7;
  const int gslot = slot ^ sub;
  const unsigned short* gk = kptr + (size_t)(wid * 8 + sub) * KVW + gslot * 8;
  const unsigned short* gv = vptr + (size_t)(wid * 8 + sub) * Nn + gslot * 8;

  bf16x8 qf[4];
  {
    const unsigned short* qrow =
        qb + ((size_t)b * Nn + q0 + r31) * Dd + h * (Gg * Cc) + g * Cc + hi * 8;
#pragma unroll
    for (int ks = 0; ks < 4; ++ks) qf[ks] = *(const bf16x8*)(qrow + ks * 16);
  }

  union { unsigned u[4]; bf16x8 v; } ones;
  ones.u[0] = ones.u[1] = ones.u[2] = ones.u[3] = 0x3F803F80u;

  int off[4];
#pragma unroll
  for (int ks = 0; ks < 4; ++ks) off[ks] = r31 * 128 + (((2 * ks + hi) ^ r7) << 4);

  f32x16 O0 = (f32x16)0.0f, O1 = (f32x16)0.0f, Lacc = (f32x16)0.0f;

  // stage one 128-key super-tile (2 K subtiles + 2 V subtiles) into buffer bi
  auto stage = [&](int bi) {
    GLOAD_LDS(gk, &Ks[bi][0][wid * 512]);
    GLOAD_LDS(gk + (size_t)64 * KVW, &Ks[bi][1][wid * 512]);
    GLOAD_LDS(gv, &Vs[bi][0][wid * 512]);
    GLOAD_LDS(gv + 64, &Vs[bi][1][wid * 512]);
    gk += (size_t)128 * KVW;
    gv += 128;
  };

  auto compute = [&](const unsigned short* Kb_, const unsigned short* Vb_) {
    const char* Kb = (const char*)Kb_;
    const char* Vb = (const char*)Vb_;
    f32x16 S0 = (f32x16)0.0f, S1 = (f32x16)0.0f;
    __builtin_amdgcn_s_setprio(1);
#pragma unroll
    for (int ks = 0; ks < 4; ++ks) {
      bf16x8 k0 = *(const bf16x8*)(Kb + off[ks]);
      bf16x8 k1 = *(const bf16x8*)(Kb + off[ks] + 4096);
      S0 = MFMA32(k0, qf[ks], S0);
      S1 = MFMA32(k1, qf[ks], S1);
    }
    __builtin_amdgcn_s_setprio(0);
    unsigned pk[16];
#pragma unroll
    for (int kt2 = 0; kt2 < 2; ++kt2)
#pragma unroll
      for (int blk = 0; blk < 4; ++blk)
#pragma unroll
        for (int m = 0; m < 2; ++m) {
          float pa = fexp2(kt2 ? S1[4 * blk + 2 * m] : S0[4 * blk + 2 * m]);
          float pb = fexp2(kt2 ? S1[4 * blk + 2 * m + 1] : S0[4 * blk + 2 * m + 1]);
          pk[kt2 * 8 + blk * 2 + m] = __builtin_amdgcn_perm(
              __float_as_uint(pb), __float_as_uint(pa), 0x07060302u);
        }
    __builtin_amdgcn_s_setprio(1);
#pragma unroll
    for (int vs = 0; vs < 4; ++vs) {
      const int base = (vs >> 1) * 8 + (vs & 1) * 4;
      u32x2 rA = __builtin_amdgcn_permlane32_swap(pk[base + 0], pk[base + 2], false, false);
      u32x2 rB = __builtin_amdgcn_permlane32_swap(pk[base + 1], pk[base + 3], false, false);
      union { unsigned u[4]; bf16x8 v; } pf;
      pf.u[0] = rA.x; pf.u[1] = rB.x; pf.u[2] = rA.y; pf.u[3] = rB.y;
      bf16x8 v0 = *(const bf16x8*)(Vb + off[vs]);
      bf16x8 v1 = *(const bf16x8*)(Vb + off[vs] + 4096);
      O0 = MFMA32(pf.v, v0, O0);
      O1 = MFMA32(pf.v, v1, O1);
      Lacc = MFMA32(pf.v, ones.v, Lacc);
    }
    __builtin_amdgcn_s_setprio(0);
  };

  stage(0);  // super-tile 0 -> buf0
  __syncthreads();
  for (int t = 0; t < Nn / 128; t += 2) {
    stage(1);                             // super-tile t+1 -> buf1, overlaps compute(t)
    compute(Ks[0][0], Vs[0][0]);
    compute(Ks[0][1], Vs[0][1]);
    __syncthreads();                      // buf0 readers done + buf1 staged
    if (t + 2 < Nn / 128) stage(0);       // super-tile t+2 -> buf0
    compute(Ks[1][0], Vs[1][0]);
    compute(Ks[1][1], Vs[1][1]);
    __syncthreads();
  }

  const size_t orow_base = (size_t)b * Nn + q0;
  const int ocol = h * (Gg * Cc) + g * Cc;
#pragma unroll
  for (int r = 0; r < 16; ++r) {
    const int q_r = (r & 3) + 8 * (r >> 2) + 4 * hi;
    const float li = 1.0f / Lacc[r];
    const size_t basep = (orow_base + q_r) * Dd + ocol;
    ob[basep + r31] = f2bf(O0[r] * li);
    ob[basep + 32 + r31] = f2bf(O1[r] * li);
  }
}

extern "C" void kernel_launch(void* const* d_in, const int* in_sizes, int n_in,
                              void* d_out, int out_size, void* d_ws, size_t ws_size,
                              hipStream_t stream) {
  const float* x   = (const float*)d_in[0];
  const float* Wq  = (const float*)d_in[1];
  const float* Wkv = (const float*)d_in[2];
  const float* Wp  = (const float*)d_in[3];
  const float* bp  = (const float*)d_in[4];
  float* out = (float*)d_out;

  char* ws = (char*)d_ws;
  size_t off = 0;
  auto alloc = [&](size_t bytes) {
    char* p = ws + off;
    off += (bytes + 255) & ~(size_t)255;
    return p;
  };
  unsigned short* xb   = (unsigned short*)alloc((size_t)Bb * Nn * Dd * 2);
  unsigned short* Wqt  = (unsigned short*)alloc((size_t)Dd * Dd * 2);
  unsigned short* Wkvt = (unsigned short*)alloc((size_t)KVW * Dd * 2);
  unsigned short* Wpt  = (unsigned short*)alloc((size_t)Dd * Dd * 2);
  unsigned short* qbf  = (unsigned short*)alloc((size_t)Bb * Nn * Dd * 2);
  unsigned short* kvb  = (unsigned short*)alloc((size_t)Bb * Nn * KVW * 2);
  unsigned short* vT   = (unsigned short*)alloc((size_t)Bb * Hh * Cc * Nn * 2);
  unsigned short* ob   = xb;  // reuse: xb dead after the KV GEMM

  const int M = Bb * Nn;  // 4096
  // 1/sqrt(32) * log2(e): softmax in exp2 domain via fexp2 (identical math)
  const float qscale = 0.17677669529663687f * 1.4426950408889634f;

  prep<<<11264, 256, 0, stream>>>(x, xb, Wq, Wqt, Wkv, Wkvt, Wp, Wpt, qscale);

  gemm_bt<128, false><<<dim3(M / 128, Dd / 128), 256, 0, stream>>>(
      xb, Wqt, qbf, nullptr, nullptr, nullptr, M, Dd, Dd);
  gemm_bt<64, false, true><<<dim3(M / 64, KVW / 128), 256, 0, stream>>>(
      xb, Wkvt, kvb, nullptr, nullptr, vT, M, KVW, Dd);
  attn_kernel<<<dim3(Nn / 256, Bb * Hh * Gg), 512, 0, stream>>>(qbf, kvb, vT, ob);
  gemm_bt<128, true><<<dim3(M / 128, Dd / 128), 256, 0, stream>>>(
      ob, Wpt, nullptr, out, bp, nullptr, M, Dd, Dd);
}